// Round 6
// baseline (175.440 us; speedup 1.0000x reference)
//
#include <hip/hip_runtime.h>
#include <float.h>
#include <math.h>

// Problem constants (reference: x shape (2,1024,32000) fp32, dim=-1, alpha=1.5)
#define D_DIM   32000
#define NT      256                         // 4 waves -> 8 blocks/CU
#define CHUNKS  (D_DIM / 4)                 // 8000 float4 chunks per row
#define KITER   ((CHUNKS + NT - 1) / NT)    // 32 strided iterations per thread
#define NGROUP  (KITER / 2)                 // 16 two-chunk groups
#define NWAVES  (NT / 64)                   // 4
#define CAPW    1248                        // per-wave pool capacity (4992 B)

typedef float f32x4 __attribute__((ext_vector_type(4)));
typedef unsigned long long ull;

__device__ __forceinline__ float waveReduceSum(float v) {
#pragma unroll
    for (int m = 32; m >= 1; m >>= 1) v += __shfl_xor(v, m, 64);
    return v;
}

__device__ __forceinline__ float waveReduceMax(float v) {
#pragma unroll
    for (int m = 32; m >= 1; m >>= 1) v = fmaxf(v, __shfl_xor(v, m, 64));
    return v;
}

// Bit-level finite scrub: maps NaN and +/-inf to -FLT_MAX. Integer-domain so
// -ffinite-math-only cannot fold it away.
__device__ __forceinline__ float scrub_finite(float v) {
    const unsigned u = __float_as_uint(v);
    if ((u & 0x7f800000u) == 0x7f800000u) return -FLT_MAX;
    return v;
}

__device__ __forceinline__ float4 ldg4(const float4* __restrict__ p, int c) {
    if (c < CHUNKS) return p[c];
    float4 r; r.x = r.y = r.z = r.w = -FLT_MAX;   // pad; *0.5 stays hugely negative
    return r;
}

// ---------------- K1: tau solver ----------------
// Streams the row once with register double-buffering (4 loads in flight).
// Candidates {z > runM-1} go into a PER-WAVE shared pool via ballot+rank
// append (deterministic). When full, wave-cooperatively evict entries
// <= runM-1 (they contribute exactly 0 to every f(tau) at tau >= max-1).
// R5 lesson: the 4-wave bisection cost ~50 block barriers/row; now a FINAL
// eviction at thr = max-1 shrinks the pools to ~600 live entries, and wave 0
// alone runs the bisection over all 4 pools barrier-free while waves 1-3
// exit. Stashes (tau_m, s_final) in the first 8 bytes of the output row.
__global__ __launch_bounds__(NT, 8)
void entmax_tau_kernel(const float* __restrict__ x, float* __restrict__ out, int rows)
{
    const int row = blockIdx.x;
    if (row >= rows) return;
    const size_t base = (size_t)row * D_DIM;
    const float4* __restrict__ xr4 = reinterpret_cast<const float4*>(x + base);

    __shared__ __align__(16) float s_pool[NWAVES * CAPW];   // 19968 B
    __shared__ float s_red[NWAVES];
    __shared__ int   s_cnt[NWAVES];
    __shared__ int   s_flag;

    const int lane = threadIdx.x & 63;
    const int wv   = threadIdx.x >> 6;
    float* __restrict__ wpool = s_pool + wv * CAPW;
    const ull lmask = (1ull << lane) - 1ull;

    if (threadIdx.x == 0) s_flag = 0;
    __syncthreads();

    // ---- pass 1: stream row (dbuf prefetch); wave max + pooled admission ----
    float runM = -FLT_MAX;
    int n = 0;           // wave-uniform pool count
    bool ovf = false;    // wave-uniform
    float4 va = ldg4(xr4, threadIdx.x);
    float4 vb = ldg4(xr4, threadIdx.x + NT);
    for (int g = 0; g < NGROUP; ++g) {
        const float4 ca = va, cb = vb;
        if (g + 1 < NGROUP) {                 // prefetch next group first
            va = ldg4(xr4, threadIdx.x + (2 * g + 2) * NT);
            vb = ldg4(xr4, threadIdx.x + (2 * g + 3) * NT);
        }
        float z[8];
        z[0] = ca.x * 0.5f; z[1] = ca.y * 0.5f; z[2] = ca.z * 0.5f; z[3] = ca.w * 0.5f;
        z[4] = cb.x * 0.5f; z[5] = cb.y * 0.5f; z[6] = cb.z * 0.5f; z[7] = cb.w * 0.5f;

        float cm = fmaxf(fmaxf(fmaxf(z[0], z[1]), fmaxf(z[2], z[3])),
                         fmaxf(fmaxf(z[4], z[5]), fmaxf(z[6], z[7])));
        cm = waveReduceMax(cm);
        runM = fmaxf(runM, cm);
        const float thr = runM - 1.0f;

        ull msk[8];
        int tot = 0;
#pragma unroll
        for (int j = 0; j < 8; ++j) {
            msk[j] = __ballot(z[j] > thr);
            tot += __popcll(msk[j]);
        }
        if (tot) {
            if (n + tot > CAPW) {
                // wave-cooperative stable compaction: keep entries > thr.
                // Within an iteration all 64 reads complete before the write
                // instr (same-wave DS ops are program-ordered); dest nn+r <=
                // src i+lane, so in-place is safe.
                int nn = 0;
                for (int i = 0; i < n; i += 64) {
                    const float v = (i + lane < n) ? wpool[i + lane] : -FLT_MAX;
                    const ull km = __ballot(v > thr);
                    const int r = __popcll(km & lmask);
                    if (v > thr) wpool[nn + r] = v;
                    nn += __popcll(km);
                }
                n = nn;
            }
            if (n + tot > CAPW) {
                ovf = true;          // adversarial/degenerate rows only
            } else {
#pragma unroll
                for (int j = 0; j < 8; ++j) {
                    if (z[j] > thr) {
                        const int r = __popcll(msk[j] & lmask);
                        wpool[n + r] = z[j];
                    }
                    n += __popcll(msk[j]);
                }
            }
        }
    }
    if (ovf && lane == 0) s_flag = 1;   // benign race across waves

    if (lane == 0) s_red[wv] = runM;
    __syncthreads();
    const float max_val = fmaxf(fmaxf(s_red[0], s_red[1]), fmaxf(s_red[2], s_red[3]));
    const int flag = s_flag;

    const float tau_lo0 = max_val - 1.0f;                   // gp(1) = 1
    const float tau_hi = max_val - 0.005590169943749474f;   // (1/32000)^0.5

    if (!flag) {
        // ---- final eviction at thr = max-1: pools shrink to the true active
        // superset (~600/row). Wave-local, in-place, deterministic. ----
        {
            int nn = 0;
            for (int i = 0; i < n; i += 64) {
                const float v = (i + lane < n) ? wpool[i + lane] : -FLT_MAX;
                const ull km = __ballot(v > tau_lo0);
                const int r = __popcll(km & lmask);
                if (v > tau_lo0) wpool[nn + r] = v;
                nn += __popcll(km);
            }
            if (lane == 0) s_cnt[wv] = nn;
        }
        __syncthreads();

        // ---- wave-0-only barrier-free bisection over all 4 pools ----
        // Waves 1-3 exit here, freeing their issue slots; pool data stays in
        // LDS until the block retires. Fixed scan order -> deterministic fp.
        if (wv == 0) {
            const int n0 = s_cnt[0], n1 = s_cnt[1], n2 = s_cnt[2], n3 = s_cnt[3];

#define POOL_SCAN(tauv, acc)                                                   \
            do {                                                               \
                const float* __restrict__ pp0 = s_pool;                        \
                for (int i = lane; i < n0; i += 64) {                          \
                    const float t = fmaxf(pp0[i] - (tauv), 0.0f);              \
                    acc = fmaf(t, t, acc);                                     \
                }                                                              \
                const float* __restrict__ pp1 = s_pool + CAPW;                 \
                for (int i = lane; i < n1; i += 64) {                          \
                    const float t = fmaxf(pp1[i] - (tauv), 0.0f);              \
                    acc = fmaf(t, t, acc);                                     \
                }                                                              \
                const float* __restrict__ pp2 = s_pool + 2 * CAPW;             \
                for (int i = lane; i < n2; i += 64) {                          \
                    const float t = fmaxf(pp2[i] - (tauv), 0.0f);              \
                    acc = fmaf(t, t, acc);                                     \
                }                                                              \
                const float* __restrict__ pp3 = s_pool + 3 * CAPW;             \
                for (int i = lane; i < n3; i += 64) {                          \
                    const float t = fmaxf(pp3[i] - (tauv), 0.0f);              \
                    acc = fmaf(t, t, acc);                                     \
                }                                                              \
            } while (0)

            float tau_lo = tau_lo0;
            float fl = 0.0f;
            POOL_SCAN(tau_lo, fl);
            fl = waveReduceSum(fl) - 1.0f;

            float dm = tau_hi - tau_lo;
            float tau_m = tau_lo;
            float s_final = 1.0f;
            for (int it = 0; it < 100; ++it) {
                dm *= 0.5f;
                tau_m = tau_lo + dm;
                const bool fixed = (tau_m == tau_lo);   // wave-uniform
                float a = 0.0f;
                POOL_SCAN(tau_m, a);
                a = waveReduceSum(a);
                s_final = a;
                if ((a - 1.0f) * fl >= 0.0f) tau_lo = tau_m;
                if (fixed) break;
            }
#undef POOL_SCAN
            if (lane == 0) {
                float2 ts; ts.x = tau_m; ts.y = s_final;
                *reinterpret_cast<float2*>(out + base) = ts;
            }
        }
    } else {
        // ---- fallback (degenerate rows only): stream row per iteration ----
        __syncthreads();   // everyone has read s_red's max components
        float tau_lo = tau_lo0;
        float acc = 0.0f;
        for (int k = 0; k < KITER; ++k) {
            const int c = threadIdx.x + k * NT;
            if (c < CHUNKS) {
                const float4 v = xr4[c];
                float t;
                t = fmaxf(v.x * 0.5f - tau_lo, 0.0f); acc = fmaf(t, t, acc);
                t = fmaxf(v.y * 0.5f - tau_lo, 0.0f); acc = fmaf(t, t, acc);
                t = fmaxf(v.z * 0.5f - tau_lo, 0.0f); acc = fmaf(t, t, acc);
                t = fmaxf(v.w * 0.5f - tau_lo, 0.0f); acc = fmaf(t, t, acc);
            }
        }
        acc = waveReduceSum(acc);
        if (lane == 0) s_red[wv] = acc;
        __syncthreads();
        const float f_lo = (s_red[0] + s_red[1] + s_red[2] + s_red[3]) - 1.0f;
        __syncthreads();

        float dm = tau_hi - tau_lo;
        float tau_m = tau_lo;
        float s_final = 1.0f;
        for (int it = 0; it < 100; ++it) {
            dm *= 0.5f;
            tau_m = tau_lo + dm;
            const bool fixed = (tau_m == tau_lo);
            float a = 0.0f;
            for (int k = 0; k < KITER; ++k) {
                const int c = threadIdx.x + k * NT;
                if (c < CHUNKS) {
                    const float4 v = xr4[c];
                    float t;
                    t = fmaxf(v.x * 0.5f - tau_m, 0.0f); a = fmaf(t, t, a);
                    t = fmaxf(v.y * 0.5f - tau_m, 0.0f); a = fmaf(t, t, a);
                    t = fmaxf(v.z * 0.5f - tau_m, 0.0f); a = fmaf(t, t, a);
                    t = fmaxf(v.w * 0.5f - tau_m, 0.0f); a = fmaf(t, t, a);
                }
            }
            a = waveReduceSum(a);
            if (lane == 0) s_red[wv] = a;
            __syncthreads();
            const float s = s_red[0] + s_red[1] + s_red[2] + s_red[3];
            __syncthreads();
            s_final = s;
            if ((s - 1.0f) * f_lo >= 0.0f) tau_lo = tau_m;
            if (fixed) break;
        }
        if (threadIdx.x == 0) {
            float2 ts; ts.x = tau_m; ts.y = s_final;
            *reinterpret_cast<float2*>(out + base) = ts;
        }
    }
}

// ---------------- K2: elementwise epilogue ----------------
// Reads the stash, then streams x -> log(p/sum) with the verified numeric
// path (floor p before log, bit-scrub residual inf/NaN), nt-stores out.
__global__ __launch_bounds__(NT, 8)
void entmax_finish_kernel(const float* __restrict__ x, float* __restrict__ out, int rows)
{
    const int row = blockIdx.x;
    if (row >= rows) return;
    const size_t base = (size_t)row * D_DIM;
    const float4* __restrict__ xr4 = reinterpret_cast<const float4*>(x + base);
    float* __restrict__ orow = out + base;

    __shared__ float2 s_ts;
    if (threadIdx.x == 0) s_ts = *reinterpret_cast<const float2*>(orow);
    __syncthreads();   // all threads see the stash before anyone overwrites it
    const float tau_m = s_ts.x;
    const float inv_s = 1.0f / s_ts.y;

    for (int k = 0; k < KITER; ++k) {
        const int c = threadIdx.x + k * NT;
        if (c < CHUNKS) {
            const float4 v = xr4[c];
            f32x4 o;
            {
                const float t = fmaxf(v.x * 0.5f - tau_m, 0.0f);
                o.x = scrub_finite(__logf(fmaxf(t * t, 1e-35f) * inv_s));
            }
            {
                const float t = fmaxf(v.y * 0.5f - tau_m, 0.0f);
                o.y = scrub_finite(__logf(fmaxf(t * t, 1e-35f) * inv_s));
            }
            {
                const float t = fmaxf(v.z * 0.5f - tau_m, 0.0f);
                o.z = scrub_finite(__logf(fmaxf(t * t, 1e-35f) * inv_s));
            }
            {
                const float t = fmaxf(v.w * 0.5f - tau_m, 0.0f);
                o.w = scrub_finite(__logf(fmaxf(t * t, 1e-35f) * inv_s));
            }
            __builtin_nontemporal_store(o, reinterpret_cast<f32x4*>(orow) + c);
        }
    }
}

extern "C" void kernel_launch(void* const* d_in, const int* in_sizes, int n_in,
                              void* d_out, int out_size, void* d_ws, size_t ws_size,
                              hipStream_t stream) {
    const float* x = (const float*)d_in[0];
    float* out = (float*)d_out;
    const int rows = in_sizes[0] / D_DIM;
    entmax_tau_kernel<<<dim3(rows), dim3(NT), 0, stream>>>(x, out, rows);
    entmax_finish_kernel<<<dim3(rows), dim3(NT), 0, stream>>>(x, out, rows);
}

// Round 7
// 146.077 us; speedup vs baseline: 1.2010x; 1.2010x over previous
//
#include <hip/hip_runtime.h>
#include <float.h>
#include <math.h>

// Problem constants (reference: x shape (2,1024,32000) fp32, dim=-1, alpha=1.5)
#define D_DIM   32000
#define NT      256                         // 4 waves -> 8 blocks/CU
#define CHUNKS  (D_DIM / 4)                 // 8000 float4 chunks per row
#define KITER   ((CHUNKS + NT - 1) / NT)    // 32 strided iterations per thread
#define NGROUP  (KITER / 2)                 // 16 two-chunk groups
#define NWAVES  (NT / 64)                   // 4
#define CAPW    1248                        // per-wave pool capacity (4992 B)

typedef float f32x4 __attribute__((ext_vector_type(4)));
typedef unsigned long long ull;

__device__ __forceinline__ float waveReduceSum(float v) {
#pragma unroll
    for (int m = 32; m >= 1; m >>= 1) v += __shfl_xor(v, m, 64);
    return v;
}

__device__ __forceinline__ float waveReduceMax(float v) {
#pragma unroll
    for (int m = 32; m >= 1; m >>= 1) v = fmaxf(v, __shfl_xor(v, m, 64));
    return v;
}

// Bit-level finite scrub: maps NaN and +/-inf to -FLT_MAX. Integer-domain so
// -ffinite-math-only cannot fold it away.
__device__ __forceinline__ float scrub_finite(float v) {
    const unsigned u = __float_as_uint(v);
    if ((u & 0x7f800000u) == 0x7f800000u) return -FLT_MAX;
    return v;
}

__device__ __forceinline__ float4 ldg4(const float4* __restrict__ p, int c) {
    if (c < CHUNKS) return p[c];
    float4 r; r.x = r.y = r.z = r.w = -FLT_MAX;   // pad; *0.5 stays hugely negative
    return r;
}

// Fused single kernel:
//  pass 1 : stream row (dbuf prefetch) -> per-wave LDS candidate pool.
//           Admission threshold = fmax(per-lane running max, LAG-4 wave max) - 1
//           (any lower bound of final max gives a superset of the active set;
//           extras contribute exactly 0 to every f(tau) at tau >= max-1).
//           The lag-4 pipeline takes the 6-deep ds_swizzle reduce chain OFF the
//           per-group critical path (R6 lesson: per-group blocking reduces).
//  bisect : final eviction at max-1, then wave 0 alone scans all 4 pools
//           barrier-free; result broadcast via LDS.
//  epilog : all waves re-read the row (L3-resident: it was streamed ~10us ago
//           by THIS block; split-kernel K2 lost that locality) and nt-store.
__global__ __launch_bounds__(NT, 8)
void entmax_log_fused(const float* __restrict__ x, float* __restrict__ out, int rows)
{
    const int row = blockIdx.x;
    if (row >= rows) return;
    const size_t base = (size_t)row * D_DIM;
    const float4* __restrict__ xr4 = reinterpret_cast<const float4*>(x + base);
    float* __restrict__ orow = out + base;

    __shared__ __align__(16) float s_pool[NWAVES * CAPW];   // 19968 B
    __shared__ float s_red[NWAVES];
    __shared__ int   s_cnt[NWAVES];
    __shared__ int   s_flag;
    __shared__ float2 s_ts;

    const int lane = threadIdx.x & 63;
    const int wv   = threadIdx.x >> 6;
    float* __restrict__ wpool = s_pool + wv * CAPW;
    const ull lmask = (1ull << lane) - 1ull;

    if (threadIdx.x == 0) s_flag = 0;
    __syncthreads();

    // ---- pass 1: stream row; lag-4 wave max + per-lane max admission ----
    float runL  = -FLT_MAX;   // per-lane running max
    float waveM = -FLT_MAX;   // wave max through group g-4 (uniform)
    float pendR = -FLT_MAX;   // in-flight reduce result (uniform when consumed)
    int n = 0;                // wave-uniform pool count
    bool ovf = false;
    float4 va = ldg4(xr4, threadIdx.x);
    float4 vb = ldg4(xr4, threadIdx.x + NT);
    for (int g = 0; g < NGROUP; ++g) {
        const float4 ca = va, cb = vb;
        if (g + 1 < NGROUP) {                 // prefetch next group first
            va = ldg4(xr4, threadIdx.x + (2 * g + 2) * NT);
            vb = ldg4(xr4, threadIdx.x + (2 * g + 3) * NT);
        }
        float z[8];
        z[0] = ca.x * 0.5f; z[1] = ca.y * 0.5f; z[2] = ca.z * 0.5f; z[3] = ca.w * 0.5f;
        z[4] = cb.x * 0.5f; z[5] = cb.y * 0.5f; z[6] = cb.z * 0.5f; z[7] = cb.w * 0.5f;

        const float cm = fmaxf(fmaxf(fmaxf(z[0], z[1]), fmaxf(z[2], z[3])),
                               fmaxf(fmaxf(z[4], z[5]), fmaxf(z[6], z[7])));
        runL = fmaxf(runL, cm);
        if ((g & 3) == 0) {
            waveM = fmaxf(waveM, pendR);      // consume reduce launched 4 groups ago
            pendR = waveReduceMax(runL);      // launch new; has 4 groups to finish
        }

        float thrL = fmaxf(runL, waveM) - 1.0f;   // per-lane, <= finalmax-1
        ull msk[8];
        int tot = 0;
#pragma unroll
        for (int j = 0; j < 8; ++j) {
            msk[j] = __ballot(z[j] > thrL);
            tot += __popcll(msk[j]);
        }
        if (tot) {
            if (n + tot > CAPW) {
                // fresh uniform wave max; evict dead entries (<= wfresh-1).
                const float wfresh = waveReduceMax(runL);
                waveM = fmaxf(waveM, wfresh);
                const float thrW = wfresh - 1.0f;
                int nn = 0;
                for (int i = 0; i < n; i += 64) {
                    const float v = (i + lane < n) ? wpool[i + lane] : -FLT_MAX;
                    const ull km = __ballot(v > thrW);
                    const int r = __popcll(km & lmask);
                    if (v > thrW) wpool[nn + r] = v;   // dest <= src: in-place safe
                    nn += __popcll(km);
                }
                n = nn;
                // re-admit this group against the tightened threshold
                thrL = fmaxf(runL, waveM) - 1.0f;
                tot = 0;
#pragma unroll
                for (int j = 0; j < 8; ++j) {
                    msk[j] = __ballot(z[j] > thrL);
                    tot += __popcll(msk[j]);
                }
            }
            if (n + tot > CAPW) {
                ovf = true;          // adversarial/degenerate rows only
            } else {
#pragma unroll
                for (int j = 0; j < 8; ++j) {
                    if (z[j] > thrL) {
                        const int r = __popcll(msk[j] & lmask);
                        wpool[n + r] = z[j];
                    }
                    n += __popcll(msk[j]);
                }
            }
        }
    }
    if (ovf && lane == 0) s_flag = 1;   // benign race across waves

    if (lane == 0) s_red[wv] = waveReduceMax(runL);   // exact final wave max
    __syncthreads();
    const float max_val = fmaxf(fmaxf(s_red[0], s_red[1]), fmaxf(s_red[2], s_red[3]));
    const int flag = s_flag;
    __syncthreads();                     // s_red is reused below

    const float tau_lo0 = max_val - 1.0f;                   // gp(1) = 1
    const float tau_hi = max_val - 0.005590169943749474f;   // (1/32000)^0.5

    if (!flag) {
        // ---- final eviction at thr = max-1 (block-uniform): pools shrink to
        // the true active superset (~600/row). Wave-local, deterministic. ----
        {
            int nn = 0;
            for (int i = 0; i < n; i += 64) {
                const float v = (i + lane < n) ? wpool[i + lane] : -FLT_MAX;
                const ull km = __ballot(v > tau_lo0);
                const int r = __popcll(km & lmask);
                if (v > tau_lo0) wpool[nn + r] = v;
                nn += __popcll(km);
            }
            if (lane == 0) s_cnt[wv] = nn;
        }
        __syncthreads();

        // ---- wave-0-only barrier-free bisection over all 4 pools ----
        if (wv == 0) {
            const int n0 = s_cnt[0], n1 = s_cnt[1], n2 = s_cnt[2], n3 = s_cnt[3];

#define POOL_SCAN(tauv, acc)                                                   \
            do {                                                               \
                const float* __restrict__ pp0 = s_pool;                        \
                for (int i = lane; i < n0; i += 64) {                          \
                    const float t = fmaxf(pp0[i] - (tauv), 0.0f);              \
                    acc = fmaf(t, t, acc);                                     \
                }                                                              \
                const float* __restrict__ pp1 = s_pool + CAPW;                 \
                for (int i = lane; i < n1; i += 64) {                          \
                    const float t = fmaxf(pp1[i] - (tauv), 0.0f);              \
                    acc = fmaf(t, t, acc);                                     \
                }                                                              \
                const float* __restrict__ pp2 = s_pool + 2 * CAPW;             \
                for (int i = lane; i < n2; i += 64) {                          \
                    const float t = fmaxf(pp2[i] - (tauv), 0.0f);              \
                    acc = fmaf(t, t, acc);                                     \
                }                                                              \
                const float* __restrict__ pp3 = s_pool + 3 * CAPW;             \
                for (int i = lane; i < n3; i += 64) {                          \
                    const float t = fmaxf(pp3[i] - (tauv), 0.0f);              \
                    acc = fmaf(t, t, acc);                                     \
                }                                                              \
            } while (0)

            float tau_lo = tau_lo0;
            float fl = 0.0f;
            POOL_SCAN(tau_lo, fl);
            fl = waveReduceSum(fl) - 1.0f;

            float dm = tau_hi - tau_lo;
            float tau_m = tau_lo;
            float s_final = 1.0f;
            for (int it = 0; it < 100; ++it) {
                dm *= 0.5f;
                tau_m = tau_lo + dm;
                const bool fixed = (tau_m == tau_lo);   // wave-uniform
                float a = 0.0f;
                POOL_SCAN(tau_m, a);
                a = waveReduceSum(a);
                s_final = a;
                if ((a - 1.0f) * fl >= 0.0f) tau_lo = tau_m;
                if (fixed) break;
            }
#undef POOL_SCAN
            if (lane == 0) { s_ts.x = tau_m; s_ts.y = s_final; }
        }
        __syncthreads();   // bisection result published
    } else {
        // ---- fallback (degenerate rows only): stream row per iteration ----
        float tau_lo = tau_lo0;
        float acc = 0.0f;
        for (int k = 0; k < KITER; ++k) {
            const int c = threadIdx.x + k * NT;
            if (c < CHUNKS) {
                const float4 v = xr4[c];
                float t;
                t = fmaxf(v.x * 0.5f - tau_lo, 0.0f); acc = fmaf(t, t, acc);
                t = fmaxf(v.y * 0.5f - tau_lo, 0.0f); acc = fmaf(t, t, acc);
                t = fmaxf(v.z * 0.5f - tau_lo, 0.0f); acc = fmaf(t, t, acc);
                t = fmaxf(v.w * 0.5f - tau_lo, 0.0f); acc = fmaf(t, t, acc);
            }
        }
        acc = waveReduceSum(acc);
        if (lane == 0) s_red[wv] = acc;
        __syncthreads();
        const float f_lo = (s_red[0] + s_red[1] + s_red[2] + s_red[3]) - 1.0f;
        __syncthreads();

        float dm = tau_hi - tau_lo;
        float tau_m = tau_lo;
        float s_final = 1.0f;
        for (int it = 0; it < 100; ++it) {
            dm *= 0.5f;
            tau_m = tau_lo + dm;
            const bool fixed = (tau_m == tau_lo);
            float a = 0.0f;
            for (int k = 0; k < KITER; ++k) {
                const int c = threadIdx.x + k * NT;
                if (c < CHUNKS) {
                    const float4 v = xr4[c];
                    float t;
                    t = fmaxf(v.x * 0.5f - tau_m, 0.0f); a = fmaf(t, t, a);
                    t = fmaxf(v.y * 0.5f - tau_m, 0.0f); a = fmaf(t, t, a);
                    t = fmaxf(v.z * 0.5f - tau_m, 0.0f); a = fmaf(t, t, a);
                    t = fmaxf(v.w * 0.5f - tau_m, 0.0f); a = fmaf(t, t, a);
                }
            }
            a = waveReduceSum(a);
            if (lane == 0) s_red[wv] = a;
            __syncthreads();
            const float s = s_red[0] + s_red[1] + s_red[2] + s_red[3];
            __syncthreads();
            s_final = s;
            if ((s - 1.0f) * f_lo >= 0.0f) tau_lo = tau_m;
            if (fixed) break;
        }
        if (threadIdx.x == 0) { s_ts.x = tau_m; s_ts.y = s_final; }
        __syncthreads();
    }

    // ---- epilogue: re-read row (L3-hot) -> log(p/sum), nt-store ----
    // Verified numeric path: floor p before log (DAZ-safe), bit-scrub residual
    // inf/NaN. nt-stores keep x resident in L3 for other blocks' rereads.
    const float tau_m = s_ts.x;
    const float inv_s = 1.0f / s_ts.y;
    for (int k = 0; k < KITER; ++k) {
        const int c = threadIdx.x + k * NT;
        if (c < CHUNKS) {
            const float4 v = xr4[c];
            f32x4 o;
            {
                const float t = fmaxf(v.x * 0.5f - tau_m, 0.0f);
                o.x = scrub_finite(__logf(fmaxf(t * t, 1e-35f) * inv_s));
            }
            {
                const float t = fmaxf(v.y * 0.5f - tau_m, 0.0f);
                o.y = scrub_finite(__logf(fmaxf(t * t, 1e-35f) * inv_s));
            }
            {
                const float t = fmaxf(v.z * 0.5f - tau_m, 0.0f);
                o.z = scrub_finite(__logf(fmaxf(t * t, 1e-35f) * inv_s));
            }
            {
                const float t = fmaxf(v.w * 0.5f - tau_m, 0.0f);
                o.w = scrub_finite(__logf(fmaxf(t * t, 1e-35f) * inv_s));
            }
            __builtin_nontemporal_store(o, reinterpret_cast<f32x4*>(orow) + c);
        }
    }
}

extern "C" void kernel_launch(void* const* d_in, const int* in_sizes, int n_in,
                              void* d_out, int out_size, void* d_ws, size_t ws_size,
                              hipStream_t stream) {
    const float* x = (const float*)d_in[0];
    float* out = (float*)d_out;
    const int rows = in_sizes[0] / D_DIM;
    entmax_log_fused<<<dim3(rows), dim3(NT), 0, stream>>>(x, out, rows);
}